// Round 1
// baseline (533.484 us; speedup 1.0000x reference)
//
#include <hip/hip_runtime.h>

using s16x8 = __attribute__((ext_vector_type(8))) short;
using f32x4 = __attribute__((ext_vector_type(4))) float;

static __device__ __forceinline__ float bf2f(unsigned short u){
  union { unsigned int i; float f; } v; v.i = ((unsigned)u) << 16; return v.f;
}
static __device__ __forceinline__ unsigned short f2bf(float f){
  union { float f; unsigned int i; } v; v.f = f;
  unsigned int x = v.i;
  return (unsigned short)((x + 0x7fffu + ((x >> 16) & 1u)) >> 16);
}

// ---------- edge-index layout detect (int32 vs int64 words) ----------
__global__ void k_detect(const int* __restrict__ ei, int nc, int* __restrict__ flag){
  if (blockIdx.x == 0 && threadIdx.x == 0){
    int all0 = 1;
    for (int i = 1; i < 2*nc; i += 2) if (ei[i] != 0) { all0 = 0; break; }
    flag[0] = all0;  // 1 => int64 storage (low words at even offsets)
  }
}

// ---------- CSR build ----------
__global__ __launch_bounds__(256) void k_count(const int* __restrict__ ei, int E,
                                               int* __restrict__ cnt, const int* __restrict__ flag){
  int i = blockIdx.x*blockDim.x + threadIdx.x;
  if (i >= E) return;
  int is64 = flag[0];
  int d = is64 ? ei[2*((size_t)E + i)] : ei[(size_t)E + i];
  atomicAdd(&cnt[d], 1);
}

__global__ __launch_bounds__(1024) void k_scan(const int* __restrict__ cnt, int* __restrict__ row_ptr,
                                               int* __restrict__ pos, int n){
  __shared__ int wsum[16];
  __shared__ int carry_sh;
  int tid = threadIdx.x, lane = tid & 63, wid = tid >> 6;
  if (tid == 0){ carry_sh = 0; row_ptr[0] = 0; }
  __syncthreads();
  for (int base = 0; base < n; base += 1024){
    int i = base + tid;
    int v = (i < n) ? cnt[i] : 0;
    int s = v;
    #pragma unroll
    for (int off = 1; off < 64; off <<= 1){
      int t = __shfl_up(s, off, 64);
      if (lane >= off) s += t;
    }
    if (lane == 63) wsum[wid] = s;
    __syncthreads();
    if (wid == 0 && lane < 16){
      int ws = wsum[lane];
      #pragma unroll
      for (int off = 1; off < 16; off <<= 1){
        int t = __shfl_up(ws, off, 64);
        if (lane >= off) ws += t;
      }
      wsum[lane] = ws;
    }
    __syncthreads();
    int carry = carry_sh;
    int wofs = (wid > 0) ? wsum[wid-1] : 0;
    int incl = carry + wofs + s;
    if (i < n){ row_ptr[i+1] = incl; pos[i] = incl - v; }
    __syncthreads();
    if (tid == 0) carry_sh = carry + wsum[15];
    __syncthreads();
  }
}

__global__ __launch_bounds__(256) void k_fill(const int* __restrict__ ei, int E,
                                              int* __restrict__ pos, int* __restrict__ srcs,
                                              const int* __restrict__ flag){
  int i = blockIdx.x*blockDim.x + threadIdx.x;
  if (i >= E) return;
  int is64 = flag[0];
  int s = is64 ? ei[2*(size_t)i] : ei[i];
  int d = is64 ? ei[2*((size_t)E + i)] : ei[(size_t)E + i];
  int p = atomicAdd(&pos[d], 1);
  srcs[p] = s;
}

// ---------- f32 -> bf16 (vector of 4) ----------
__global__ __launch_bounds__(256) void k_cvt4(const float* __restrict__ in,
                                              unsigned short* __restrict__ out, int n4){
  int i = blockIdx.x*blockDim.x + threadIdx.x;
  if (i >= n4) return;
  float4 v = ((const float4*)in)[i];
  ushort4 o; o.x = f2bf(v.x); o.y = f2bf(v.y); o.z = f2bf(v.z); o.w = f2bf(v.w);
  ((ushort4*)out)[i] = o;
}

// ---------- combined post-MLP weights: Wc = Wp2 @ Wp1, bc = Wp2 @ bp1 + bp2 ----------
__global__ __launch_bounds__(256) void k_make_wc(const float* __restrict__ Wp1, const float* __restrict__ bp1,
                                                 const float* __restrict__ Wp2, const float* __restrict__ bp2,
                                                 unsigned short* __restrict__ Wc, float* __restrict__ bc){
  int idx = blockIdx.x*blockDim.x + threadIdx.x;
  if (idx >= 64*128) return;
  int o = idx >> 7, k = idx & 127;
  float s = 0.f;
  for (int j = 0; j < 128; ++j) s += Wp2[o*128 + j] * Wp1[j*128 + k];
  Wc[o*128 + k] = f2bf(s);
  if (k == 0){
    float t = bp2[o];
    for (int j = 0; j < 128; ++j) t += Wp2[o*128 + j] * bp1[j];
    bc[o] = t;
  }
}

// ---------- mean aggregation: one wave per node, 2 feats per lane ----------
__global__ __launch_bounds__(256) void k_agg(const unsigned short* __restrict__ h,
                                             const int* __restrict__ row_ptr,
                                             const int* __restrict__ srcs,
                                             unsigned short* __restrict__ mean, int N){
  int node = blockIdx.x*4 + (threadIdx.x >> 6);
  if (node >= N) return;
  int f2 = threadIdx.x & 63;          // features 2*f2, 2*f2+1
  int beg = row_ptr[node], end = row_ptr[node+1];
  float s0 = 0.f, s1 = 0.f;
  for (int e = beg; e < end; ++e){
    int sidx = srcs[e];
    unsigned int v = *(const unsigned int*)(h + (size_t)sidx*128 + f2*2);
    s0 += bf2f((unsigned short)(v & 0xffffu));
    s1 += bf2f((unsigned short)(v >> 16));
  }
  float c = fmaxf((float)(end - beg), 1.f);
  float inv = 1.f / c;
  unsigned int o = ((unsigned int)f2bf(s1*inv) << 16) | f2bf(s0*inv);
  *(unsigned int*)(mean + (size_t)node*128 + f2*2) = o;
}

// ---------- fused SAGE layer GEMM: out = relu(mean@Wl^T + b + h@Wr^T), bf16 MFMA ----------
__global__ __launch_bounds__(256) void k_gemm(const unsigned short* __restrict__ mean,
                                              const unsigned short* __restrict__ hin,
                                              const unsigned short* __restrict__ Wl,
                                              const unsigned short* __restrict__ Wr,
                                              const float* __restrict__ bias,
                                              unsigned short* __restrict__ hout, int N){
  int wave = threadIdx.x >> 6;
  int lane = threadIdx.x & 63;
  int row0 = (blockIdx.x*4 + wave) * 16;
  if (row0 >= N) return;
  int lr = lane & 15;
  int kg = lane >> 4;
  int row = row0 + lr; if (row >= N) row = N - 1;

  s16x8 a[8];
  const unsigned short* mrow = mean + (size_t)row*128;
  const unsigned short* hrow = hin  + (size_t)row*128;
  #pragma unroll
  for (int t = 0; t < 4; ++t) a[t]   = *(const s16x8*)(mrow + t*32 + kg*8);
  #pragma unroll
  for (int t = 0; t < 4; ++t) a[4+t] = *(const s16x8*)(hrow + t*32 + kg*8);

  #pragma unroll
  for (int jt = 0; jt < 8; ++jt){
    f32x4 acc = {0.f, 0.f, 0.f, 0.f};
    int j = jt*16 + lr;
    const unsigned short* wlrow = Wl + (size_t)j*128;
    const unsigned short* wrrow = Wr + (size_t)j*128;
    #pragma unroll
    for (int t = 0; t < 4; ++t){
      s16x8 b = *(const s16x8*)(wlrow + t*32 + kg*8);
      acc = __builtin_amdgcn_mfma_f32_16x16x32_bf16(a[t], b, acc, 0, 0, 0);
    }
    #pragma unroll
    for (int t = 0; t < 4; ++t){
      s16x8 b = *(const s16x8*)(wrrow + t*32 + kg*8);
      acc = __builtin_amdgcn_mfma_f32_16x16x32_bf16(a[4+t], b, acc, 0, 0, 0);
    }
    int ocol = jt*16 + lr;
    float bv = bias[ocol];
    #pragma unroll
    for (int i = 0; i < 4; ++i){
      int orow = row0 + kg*4 + i;
      if (orow < N){
        float v = acc[i] + bv;
        v = fmaxf(v, 0.f);
        hout[(size_t)orow*128 + ocol] = f2bf(v);
      }
    }
  }
}

// ---------- fused head: logits (bf16 MFMA) + log_softmax, fp32 out ----------
__global__ __launch_bounds__(256) void k_post(const unsigned short* __restrict__ h,
                                              const unsigned short* __restrict__ Wc,
                                              const float* __restrict__ bc,
                                              float* __restrict__ out, int N){
  int wave = threadIdx.x >> 6;
  int lane = threadIdx.x & 63;
  int row0 = (blockIdx.x*4 + wave) * 16;
  if (row0 >= N) return;
  int lr = lane & 15;
  int kg = lane >> 4;
  int row = row0 + lr; if (row >= N) row = N - 1;

  s16x8 a[4];
  const unsigned short* hrow = h + (size_t)row*128;
  #pragma unroll
  for (int t = 0; t < 4; ++t) a[t] = *(const s16x8*)(hrow + t*32 + kg*8);

  float v[4][4];   // [jt][i]
  #pragma unroll
  for (int jt = 0; jt < 4; ++jt){
    f32x4 acc = {0.f, 0.f, 0.f, 0.f};
    int j = jt*16 + lr;
    const unsigned short* wrow = Wc + (size_t)j*128;
    #pragma unroll
    for (int t = 0; t < 4; ++t){
      s16x8 b = *(const s16x8*)(wrow + t*32 + kg*8);
      acc = __builtin_amdgcn_mfma_f32_16x16x32_bf16(a[t], b, acc, 0, 0, 0);
    }
    float bv = bc[jt*16 + lr];
    #pragma unroll
    for (int i = 0; i < 4; ++i) v[jt][i] = acc[i] + bv;
  }

  #pragma unroll
  for (int i = 0; i < 4; ++i){
    float m = v[0][i];
    #pragma unroll
    for (int jt = 1; jt < 4; ++jt) m = fmaxf(m, v[jt][i]);
    #pragma unroll
    for (int msk = 1; msk < 16; msk <<= 1) m = fmaxf(m, __shfl_xor(m, msk, 64));
    float s = 0.f;
    #pragma unroll
    for (int jt = 0; jt < 4; ++jt) s += expf(v[jt][i] - m);
    #pragma unroll
    for (int msk = 1; msk < 16; msk <<= 1) s += __shfl_xor(s, msk, 64);
    float lse = m + logf(s);
    int orow = row0 + kg*4 + i;
    if (orow < N){
      #pragma unroll
      for (int jt = 0; jt < 4; ++jt)
        out[(size_t)orow*64 + jt*16 + lr] = v[jt][i] - lse;
    }
  }
}

extern "C" void kernel_launch(void* const* d_in, const int* in_sizes, int n_in,
                              void* d_out, int out_size, void* d_ws, size_t ws_size,
                              hipStream_t stream){
  const int N = in_sizes[0] / 128;
  const int E = in_sizes[1] / 2;
  if (N <= 0 || E <= 0) return;

  const float* x   = (const float*)d_in[0];
  const int*   ei  = (const int*)d_in[1];
  const float* Wl[3] = {(const float*)d_in[2], (const float*)d_in[5], (const float*)d_in[8]};
  const float* bl[3] = {(const float*)d_in[3], (const float*)d_in[6], (const float*)d_in[9]};
  const float* Wr[3] = {(const float*)d_in[4], (const float*)d_in[7], (const float*)d_in[10]};
  const float* Wp1 = (const float*)d_in[11];
  const float* bp1 = (const float*)d_in[12];
  const float* Wp2 = (const float*)d_in[13];
  const float* bp2 = (const float*)d_in[14];
  float* out = (float*)d_out;

  char* p = (char*)d_ws;
  auto alloc = [&](size_t bytes){ char* r = p; p += (bytes + 255) & ~(size_t)255; return r; };
  unsigned short* xb   = (unsigned short*)alloc((size_t)N*128*2);
  unsigned short* hA   = (unsigned short*)alloc((size_t)N*128*2);
  unsigned short* hB   = (unsigned short*)alloc((size_t)N*128*2);
  unsigned short* mean = (unsigned short*)alloc((size_t)N*128*2);
  unsigned short* wlb[3], *wrb[3];
  for (int l = 0; l < 3; ++l){
    wlb[l] = (unsigned short*)alloc(128*128*2);
    wrb[l] = (unsigned short*)alloc(128*128*2);
  }
  unsigned short* wc = (unsigned short*)alloc(64*128*2);
  float* bc   = (float*)alloc(64*4);
  int* cnt    = (int*)alloc((size_t)N*4);
  int* rowp   = (int*)alloc((size_t)(N+1)*4);
  int* pos    = (int*)alloc((size_t)N*4);
  int* srcs   = (int*)alloc((size_t)E*4);
  int* eflag  = (int*)alloc(4);

  hipMemsetAsync(cnt, 0, (size_t)N*4, stream);
  k_detect<<<1, 1, 0, stream>>>(ei, (E < 64 ? E : 64), eflag);
  k_count<<<(E + 255)/256, 256, 0, stream>>>(ei, E, cnt, eflag);
  k_scan<<<1, 1024, 0, stream>>>(cnt, rowp, pos, N);
  k_fill<<<(E + 255)/256, 256, 0, stream>>>(ei, E, pos, srcs, eflag);

  k_cvt4<<<((N*128/4) + 255)/256, 256, 0, stream>>>(x, xb, N*128/4);
  for (int l = 0; l < 3; ++l){
    k_cvt4<<<16, 256, 0, stream>>>(Wl[l], wlb[l], 128*128/4);
    k_cvt4<<<16, 256, 0, stream>>>(Wr[l], wrb[l], 128*128/4);
  }
  k_make_wc<<<32, 256, 0, stream>>>(Wp1, bp1, Wp2, bp2, wc, bc);

  int waves = (N + 15)/16;
  int gblocks = (waves + 3)/4;
  const unsigned short* hin = xb;
  unsigned short* houts[3] = {hA, hB, hA};
  for (int l = 0; l < 3; ++l){
    k_agg<<<(N + 3)/4, 256, 0, stream>>>(hin, rowp, srcs, mean, N);
    k_gemm<<<gblocks, 256, 0, stream>>>(mean, hin, wlb[l], wrb[l], bl[l], houts[l], N);
    hin = houts[l];
  }
  k_post<<<gblocks, 256, 0, stream>>>(hin, wc, bc, out, N);
}

// Round 2
// 350.142 us; speedup vs baseline: 1.5236x; 1.5236x over previous
//
#include <hip/hip_runtime.h>

using s16x8 = __attribute__((ext_vector_type(8))) short;
using f32x4 = __attribute__((ext_vector_type(4))) float;

static __device__ __forceinline__ float bf2f(unsigned short u){
  union { unsigned int i; float f; } v; v.i = ((unsigned)u) << 16; return v.f;
}
static __device__ __forceinline__ unsigned short f2bf(float f){
  union { float f; unsigned int i; } v; v.f = f;
  unsigned int x = v.i;
  return (unsigned short)((x + 0x7fffu + ((x >> 16) & 1u)) >> 16);
}

// ---------- edge-index layout detect (int32 vs int64 words) ----------
__global__ void k_detect(const int* __restrict__ ei, int nc, int* __restrict__ flag){
  if (blockIdx.x == 0 && threadIdx.x == 0){
    int all0 = 1;
    for (int i = 1; i < 2*nc; i += 2) if (ei[i] != 0) { all0 = 0; break; }
    flag[0] = all0;  // 1 => int64 storage (low words at even offsets)
  }
}

// ---------- CSR build ----------
__global__ __launch_bounds__(256) void k_count(const int* __restrict__ ei, int E,
                                               int* __restrict__ cnt, const int* __restrict__ flag){
  int i = blockIdx.x*blockDim.x + threadIdx.x;
  if (i >= E) return;
  int is64 = flag[0];
  int d = is64 ? ei[2*((size_t)E + i)] : ei[(size_t)E + i];
  atomicAdd(&cnt[d], 1);
}

// hierarchical scan: per-block (2048 elems) inclusive partials + block sums
__global__ __launch_bounds__(256) void k_scan_blk(const int* __restrict__ cnt,
                                                  int* __restrict__ rowp,
                                                  int* __restrict__ bsum, int n){
  __shared__ int wtot[4];
  int tid = threadIdx.x, lane = tid & 63, wid = tid >> 6;
  int base = blockIdx.x * 2048 + tid * 8;
  int v[8];
  #pragma unroll
  for (int j = 0; j < 8; ++j){
    int i = base + j;
    v[j] = (i < n) ? cnt[i] : 0;
  }
  #pragma unroll
  for (int j = 1; j < 8; ++j) v[j] += v[j-1];
  int t = v[7];
  int s = t;
  #pragma unroll
  for (int off = 1; off < 64; off <<= 1){
    int u = __shfl_up(s, off, 64);
    if (lane >= off) s += u;
  }
  if (lane == 63) wtot[wid] = s;
  __syncthreads();
  int wofs = 0;
  #pragma unroll
  for (int w = 0; w < 4; ++w) if (w < wid) wofs += wtot[w];
  int tofs = wofs + s - t;   // exclusive offset of this thread's first elem within block
  #pragma unroll
  for (int j = 0; j < 8; ++j){
    int i = base + j;
    if (i < n) rowp[i+1] = tofs + v[j];   // block-local inclusive
  }
  if (tid == 255) bsum[blockIdx.x] = wofs + s;  // block total
}

__global__ void k_scan_top(const int* __restrict__ bsum, int* __restrict__ bofs, int nb){
  int lane = threadIdx.x & 63;
  int carry = 0;
  for (int base = 0; base < nb; base += 64){
    int i = base + lane;
    int vv = (i < nb) ? bsum[i] : 0;
    int s = vv;
    #pragma unroll
    for (int off = 1; off < 64; off <<= 1){
      int u = __shfl_up(s, off, 64);
      if (lane >= off) s += u;
    }
    if (i < nb) bofs[i] = carry + s - vv;
    carry += __shfl(s, 63, 64);
  }
}

__global__ __launch_bounds__(256) void k_scan_add(const int* __restrict__ cnt,
                                                  int* __restrict__ rowp,
                                                  int* __restrict__ pos,
                                                  const int* __restrict__ bofs, int n){
  int i = blockIdx.x*blockDim.x + threadIdx.x;
  if (i == 0) rowp[0] = 0;
  if (i >= n) return;
  int off = bofs[i >> 11];
  int incl = rowp[i+1] + off;
  rowp[i+1] = incl;
  pos[i] = incl - cnt[i];
}

__global__ __launch_bounds__(256) void k_fill(const int* __restrict__ ei, int E,
                                              int* __restrict__ pos, int* __restrict__ srcs,
                                              const int* __restrict__ flag){
  int i = blockIdx.x*blockDim.x + threadIdx.x;
  if (i >= E) return;
  int is64 = flag[0];
  int s = is64 ? ei[2*(size_t)i] : ei[i];
  int d = is64 ? ei[2*((size_t)E + i)] : ei[(size_t)E + i];
  int p = atomicAdd(&pos[d], 1);
  srcs[p] = s;
}

// ---------- f32 -> bf16 (vector of 4) ----------
__global__ __launch_bounds__(256) void k_cvt4(const float* __restrict__ in,
                                              unsigned short* __restrict__ out, int n4){
  int i = blockIdx.x*blockDim.x + threadIdx.x;
  if (i >= n4) return;
  float4 v = ((const float4*)in)[i];
  ushort4 o; o.x = f2bf(v.x); o.y = f2bf(v.y); o.z = f2bf(v.z); o.w = f2bf(v.w);
  ((ushort4*)out)[i] = o;
}

// ---------- combined post-MLP weights: Wc = Wp2 @ Wp1, bc = Wp2 @ bp1 + bp2 ----------
__global__ __launch_bounds__(256) void k_make_wc(const float* __restrict__ Wp1, const float* __restrict__ bp1,
                                                 const float* __restrict__ Wp2, const float* __restrict__ bp2,
                                                 unsigned short* __restrict__ Wc, float* __restrict__ bc){
  int idx = blockIdx.x*blockDim.x + threadIdx.x;
  if (idx >= 64*128) return;
  int o = idx >> 7, k = idx & 127;
  float s = 0.f;
  for (int j = 0; j < 128; ++j) s += Wp2[o*128 + j] * Wp1[j*128 + k];
  Wc[o*128 + k] = f2bf(s);
  if (k == 0){
    float t = bp2[o];
    for (int j = 0; j < 128; ++j) t += Wp2[o*128 + j] * bp1[j];
    bc[o] = t;
  }
}

// ---------- mean aggregation: one wave per node, 2 feats per lane, 8-deep MLP ----------
__global__ __launch_bounds__(256) void k_agg(const unsigned short* __restrict__ h,
                                             const int* __restrict__ row_ptr,
                                             const int* __restrict__ srcs,
                                             unsigned short* __restrict__ mean, int N){
  int node = blockIdx.x*4 + (threadIdx.x >> 6);
  if (node >= N) return;
  int f2 = threadIdx.x & 63;          // features 2*f2, 2*f2+1
  int beg = row_ptr[node], end = row_ptr[node+1];
  float s0 = 0.f, s1 = 0.f;
  int e = beg;
  // 8-deep unroll: 8 independent 256B gathers in flight per wave
  for (; e + 8 <= end; e += 8){
    int idx[8];
    #pragma unroll
    for (int j = 0; j < 8; ++j) idx[j] = srcs[e + j];
    unsigned int vv[8];
    #pragma unroll
    for (int j = 0; j < 8; ++j)
      vv[j] = *(const unsigned int*)(h + (size_t)idx[j]*128 + f2*2);
    #pragma unroll
    for (int j = 0; j < 8; ++j){
      s0 += bf2f((unsigned short)(vv[j] & 0xffffu));
      s1 += bf2f((unsigned short)(vv[j] >> 16));
    }
  }
  for (; e + 4 <= end; e += 4){
    int idx[4];
    #pragma unroll
    for (int j = 0; j < 4; ++j) idx[j] = srcs[e + j];
    unsigned int vv[4];
    #pragma unroll
    for (int j = 0; j < 4; ++j)
      vv[j] = *(const unsigned int*)(h + (size_t)idx[j]*128 + f2*2);
    #pragma unroll
    for (int j = 0; j < 4; ++j){
      s0 += bf2f((unsigned short)(vv[j] & 0xffffu));
      s1 += bf2f((unsigned short)(vv[j] >> 16));
    }
  }
  for (; e < end; ++e){
    int sidx = srcs[e];
    unsigned int v = *(const unsigned int*)(h + (size_t)sidx*128 + f2*2);
    s0 += bf2f((unsigned short)(v & 0xffffu));
    s1 += bf2f((unsigned short)(v >> 16));
  }
  float c = fmaxf((float)(end - beg), 1.f);
  float inv = 1.f / c;
  unsigned int o = ((unsigned int)f2bf(s1*inv) << 16) | f2bf(s0*inv);
  *(unsigned int*)(mean + (size_t)node*128 + f2*2) = o;
}

// ---------- fused SAGE layer GEMM: out = relu(mean@Wl^T + b + h@Wr^T), bf16 MFMA ----------
__global__ __launch_bounds__(256) void k_gemm(const unsigned short* __restrict__ mean,
                                              const unsigned short* __restrict__ hin,
                                              const unsigned short* __restrict__ Wl,
                                              const unsigned short* __restrict__ Wr,
                                              const float* __restrict__ bias,
                                              unsigned short* __restrict__ hout, int N){
  int wave = threadIdx.x >> 6;
  int lane = threadIdx.x & 63;
  int row0 = (blockIdx.x*4 + wave) * 16;
  if (row0 >= N) return;
  int lr = lane & 15;
  int kg = lane >> 4;
  int row = row0 + lr; if (row >= N) row = N - 1;

  s16x8 a[8];
  const unsigned short* mrow = mean + (size_t)row*128;
  const unsigned short* hrow = hin  + (size_t)row*128;
  #pragma unroll
  for (int t = 0; t < 4; ++t) a[t]   = *(const s16x8*)(mrow + t*32 + kg*8);
  #pragma unroll
  for (int t = 0; t < 4; ++t) a[4+t] = *(const s16x8*)(hrow + t*32 + kg*8);

  #pragma unroll
  for (int jt = 0; jt < 8; ++jt){
    f32x4 acc = {0.f, 0.f, 0.f, 0.f};
    int j = jt*16 + lr;
    const unsigned short* wlrow = Wl + (size_t)j*128;
    const unsigned short* wrrow = Wr + (size_t)j*128;
    #pragma unroll
    for (int t = 0; t < 4; ++t){
      s16x8 b = *(const s16x8*)(wlrow + t*32 + kg*8);
      acc = __builtin_amdgcn_mfma_f32_16x16x32_bf16(a[t], b, acc, 0, 0, 0);
    }
    #pragma unroll
    for (int t = 0; t < 4; ++t){
      s16x8 b = *(const s16x8*)(wrrow + t*32 + kg*8);
      acc = __builtin_amdgcn_mfma_f32_16x16x32_bf16(a[4+t], b, acc, 0, 0, 0);
    }
    int ocol = jt*16 + lr;
    float bv = bias[ocol];
    #pragma unroll
    for (int i = 0; i < 4; ++i){
      int orow = row0 + kg*4 + i;
      if (orow < N){
        float v = acc[i] + bv;
        v = fmaxf(v, 0.f);
        hout[(size_t)orow*128 + ocol] = f2bf(v);
      }
    }
  }
}

// ---------- fused head: logits (bf16 MFMA) + log_softmax, fp32 out ----------
__global__ __launch_bounds__(256) void k_post(const unsigned short* __restrict__ h,
                                              const unsigned short* __restrict__ Wc,
                                              const float* __restrict__ bc,
                                              float* __restrict__ out, int N){
  int wave = threadIdx.x >> 6;
  int lane = threadIdx.x & 63;
  int row0 = (blockIdx.x*4 + wave) * 16;
  if (row0 >= N) return;
  int lr = lane & 15;
  int kg = lane >> 4;
  int row = row0 + lr; if (row >= N) row = N - 1;

  s16x8 a[4];
  const unsigned short* hrow = h + (size_t)row*128;
  #pragma unroll
  for (int t = 0; t < 4; ++t) a[t] = *(const s16x8*)(hrow + t*32 + kg*8);

  float v[4][4];   // [jt][i]
  #pragma unroll
  for (int jt = 0; jt < 4; ++jt){
    f32x4 acc = {0.f, 0.f, 0.f, 0.f};
    int j = jt*16 + lr;
    const unsigned short* wrow = Wc + (size_t)j*128;
    #pragma unroll
    for (int t = 0; t < 4; ++t){
      s16x8 b = *(const s16x8*)(wrow + t*32 + kg*8);
      acc = __builtin_amdgcn_mfma_f32_16x16x32_bf16(a[t], b, acc, 0, 0, 0);
    }
    float bv = bc[jt*16 + lr];
    #pragma unroll
    for (int i = 0; i < 4; ++i) v[jt][i] = acc[i] + bv;
  }

  #pragma unroll
  for (int i = 0; i < 4; ++i){
    float m = v[0][i];
    #pragma unroll
    for (int jt = 1; jt < 4; ++jt) m = fmaxf(m, v[jt][i]);
    #pragma unroll
    for (int msk = 1; msk < 16; msk <<= 1) m = fmaxf(m, __shfl_xor(m, msk, 64));
    float s = 0.f;
    #pragma unroll
    for (int jt = 0; jt < 4; ++jt) s += expf(v[jt][i] - m);
    #pragma unroll
    for (int msk = 1; msk < 16; msk <<= 1) s += __shfl_xor(s, msk, 64);
    float lse = m + logf(s);
    int orow = row0 + kg*4 + i;
    if (orow < N){
      #pragma unroll
      for (int jt = 0; jt < 4; ++jt)
        out[(size_t)orow*64 + jt*16 + lr] = v[jt][i] - lse;
    }
  }
}

extern "C" void kernel_launch(void* const* d_in, const int* in_sizes, int n_in,
                              void* d_out, int out_size, void* d_ws, size_t ws_size,
                              hipStream_t stream){
  const int N = in_sizes[0] / 128;
  const int E = in_sizes[1] / 2;
  if (N <= 0 || E <= 0) return;

  const float* x   = (const float*)d_in[0];
  const int*   ei  = (const int*)d_in[1];
  const float* Wl[3] = {(const float*)d_in[2], (const float*)d_in[5], (const float*)d_in[8]};
  const float* bl[3] = {(const float*)d_in[3], (const float*)d_in[6], (const float*)d_in[9]};
  const float* Wr[3] = {(const float*)d_in[4], (const float*)d_in[7], (const float*)d_in[10]};
  const float* Wp1 = (const float*)d_in[11];
  const float* bp1 = (const float*)d_in[12];
  const float* Wp2 = (const float*)d_in[13];
  const float* bp2 = (const float*)d_in[14];
  float* out = (float*)d_out;

  char* p = (char*)d_ws;
  auto alloc = [&](size_t bytes){ char* r = p; p += (bytes + 255) & ~(size_t)255; return r; };
  unsigned short* xb   = (unsigned short*)alloc((size_t)N*128*2);
  unsigned short* hA   = (unsigned short*)alloc((size_t)N*128*2);
  unsigned short* hB   = (unsigned short*)alloc((size_t)N*128*2);
  unsigned short* mean = (unsigned short*)alloc((size_t)N*128*2);
  unsigned short* wlb[3], *wrb[3];
  for (int l = 0; l < 3; ++l){
    wlb[l] = (unsigned short*)alloc(128*128*2);
    wrb[l] = (unsigned short*)alloc(128*128*2);
  }
  unsigned short* wc = (unsigned short*)alloc(64*128*2);
  float* bc   = (float*)alloc(64*4);
  int* cnt    = (int*)alloc((size_t)N*4);
  int* rowp   = (int*)alloc((size_t)(N+1)*4);
  int* pos    = (int*)alloc((size_t)N*4);
  int* srcs   = (int*)alloc((size_t)E*4);
  int* eflag  = (int*)alloc(4);
  int  nb     = (N + 2047) / 2048;
  int* bsum   = (int*)alloc((size_t)nb*4);
  int* bofs   = (int*)alloc((size_t)nb*4);

  hipMemsetAsync(cnt, 0, (size_t)N*4, stream);
  k_detect<<<1, 1, 0, stream>>>(ei, (E < 64 ? E : 64), eflag);
  k_count<<<(E + 255)/256, 256, 0, stream>>>(ei, E, cnt, eflag);
  k_scan_blk<<<nb, 256, 0, stream>>>(cnt, rowp, bsum, N);
  k_scan_top<<<1, 64, 0, stream>>>(bsum, bofs, nb);
  k_scan_add<<<(N + 255)/256, 256, 0, stream>>>(cnt, rowp, pos, bofs, N);
  k_fill<<<(E + 255)/256, 256, 0, stream>>>(ei, E, pos, srcs, eflag);

  k_cvt4<<<((N*128/4) + 255)/256, 256, 0, stream>>>(x, xb, N*128/4);
  for (int l = 0; l < 3; ++l){
    k_cvt4<<<16, 256, 0, stream>>>(Wl[l], wlb[l], 128*128/4);
    k_cvt4<<<16, 256, 0, stream>>>(Wr[l], wrb[l], 128*128/4);
  }
  k_make_wc<<<32, 256, 0, stream>>>(Wp1, bp1, Wp2, bp2, wc, bc);

  int waves = (N + 15)/16;
  int gblocks = (waves + 3)/4;
  const unsigned short* hin = xb;
  unsigned short* houts[3] = {hA, hB, hA};
  for (int l = 0; l < 3; ++l){
    k_agg<<<(N + 3)/4, 256, 0, stream>>>(hin, rowp, srcs, mean, N);
    k_gemm<<<gblocks, 256, 0, stream>>>(mean, hin, wlb[l], wrb[l], bl[l], houts[l], N);
    hin = houts[l];
  }
  k_post<<<gblocks, 256, 0, stream>>>(hin, wc, bc, out, N);
}